// Round 1
// baseline (560.649 us; speedup 1.0000x reference)
//
#include <hip/hip_runtime.h>
#include <hip/hip_bf16.h>

#define NN 100000
#define NE 3200000
#define NF 512
#define NH 16
#define NC 40

typedef __attribute__((ext_vector_type(4))) float f32x4;
typedef __attribute__((ext_vector_type(8))) short bf16x8;

static __device__ __forceinline__ unsigned short f2b(float f) {
    unsigned int u = __float_as_uint(f);
    u += 0x7FFFu + ((u >> 16) & 1u);   // round-to-nearest-even
    return (unsigned short)(u >> 16);
}

// ---------------- CSR build ----------------

__global__ void k_hist(const int* __restrict__ ei, int* __restrict__ cnt) {
    int e = blockIdx.x * blockDim.x + threadIdx.x;
    if (e < NE) atomicAdd(&cnt[ei[NE + e]], 1);
}

__global__ void k_bsum(const int* __restrict__ cnt, int* __restrict__ bsum) {
    __shared__ int red[256];
    int i = blockIdx.x * 256 + threadIdx.x;
    int v = (i < NN) ? cnt[i] : 0;
    red[threadIdx.x] = v;
    __syncthreads();
    for (int s = 128; s > 0; s >>= 1) {
        if (threadIdx.x < s) red[threadIdx.x] += red[threadIdx.x + s];
        __syncthreads();
    }
    if (threadIdx.x == 0) bsum[blockIdx.x] = red[0];
}

__global__ void k_scanb(int* __restrict__ bsum, int nb) {
    __shared__ int sh[512];
    int t = threadIdx.x;
    int v = (t < nb) ? bsum[t] : 0;
    sh[t] = v;
    __syncthreads();
    for (int off = 1; off < 512; off <<= 1) {
        int add = (t >= off) ? sh[t - off] : 0;
        __syncthreads();
        sh[t] += add;
        __syncthreads();
    }
    if (t < nb) bsum[t] = sh[t] - v;  // exclusive
}

__global__ void k_scanc(const int* __restrict__ cnt, const int* __restrict__ bsum,
                        int* __restrict__ rowptr, int* __restrict__ fillpos,
                        float* __restrict__ dinv) {
    __shared__ int sh[256];
    int i = blockIdx.x * 256 + threadIdx.x;
    int v = (i < NN) ? cnt[i] : 0;
    sh[threadIdx.x] = v;
    __syncthreads();
    for (int off = 1; off < 256; off <<= 1) {
        int add = (threadIdx.x >= off) ? sh[threadIdx.x - off] : 0;
        __syncthreads();
        sh[threadIdx.x] += add;
        __syncthreads();
    }
    if (i < NN) {
        int start = bsum[blockIdx.x] + sh[threadIdx.x] - v;
        rowptr[i] = start;
        fillpos[i] = start;
        dinv[i] = rsqrtf((float)(v + 1));   // deg includes self-loop, always >= 1
        if (i == NN - 1) rowptr[NN] = start + v;
    }
}

__global__ void k_fill(const int* __restrict__ ei, int* __restrict__ fillpos,
                       int* __restrict__ ssrc) {
    int e = blockIdx.x * blockDim.x + threadIdx.x;
    if (e < NE) {
        int s = ei[e], d = ei[NE + e];
        int p = atomicAdd(&fillpos[d], 1);
        ssrc[p] = s;
    }
}

// ---------------- W1 pack (per-lane MFMA B-fragment layout, f32 -> bf16) ----------------
// idx = (s*64 + l)*8 + e  holds  W1[32*s + (l>>4)*8 + e][l&15]

__global__ void k_packW1(const float* __restrict__ W1, unsigned short* __restrict__ pack) {
    int idx = blockIdx.x * 256 + threadIdx.x;   // 16*64*8 = 8192 total
    int s = idx >> 9;
    int l = (idx >> 3) & 63;
    int e = idx & 7;
    int k = s * 32 + (l >> 4) * 8 + e;
    int col = l & 15;
    pack[idx] = f2b(W1[k * 16 + col]);
}

// ---------------- GEMM1: h1[100000][16] = X[100000][512] @ W1 (bf16 MFMA) ----------------

__global__ void __launch_bounds__(256) k_gemm1(const float* __restrict__ x,
                                               const unsigned short* __restrict__ wp,
                                               float* __restrict__ h1) {
    int wave = threadIdx.x >> 6;
    int l = threadIdx.x & 63;
    int m0 = blockIdx.x * 64 + wave * 16;
    if (m0 >= NN) return;                        // NN % 16 == 0, waves fully in/out
    int row = m0 + (l & 15);
    int krow = (l >> 4) * 8;
    const float* xr = x + (size_t)row * NF + krow;
    const unsigned short* wl = wp + l * 8;

    f32x4 acc = {0.f, 0.f, 0.f, 0.f};
#pragma unroll 4
    for (int s = 0; s < 16; ++s) {
        f32x4 xa = *(const f32x4*)(xr + s * 32);
        f32x4 xb = *(const f32x4*)(xr + s * 32 + 4);
        union { bf16x8 v; unsigned short u[8]; } a;
        a.u[0] = f2b(xa.x); a.u[1] = f2b(xa.y); a.u[2] = f2b(xa.z); a.u[3] = f2b(xa.w);
        a.u[4] = f2b(xb.x); a.u[5] = f2b(xb.y); a.u[6] = f2b(xb.z); a.u[7] = f2b(xb.w);
        bf16x8 b = *(const bf16x8*)(wl + s * 512);
        acc = __builtin_amdgcn_mfma_f32_16x16x32_bf16(a.v, b, acc, 0, 0, 0);
    }
    // C layout: col = l&15, row = (l>>4)*4 + r   [m89-verified]
#pragma unroll
    for (int r = 0; r < 4; ++r) {
        int orow = m0 + (l >> 4) * 4 + r;
        h1[(size_t)orow * NH + (l & 15)] = acc[r];
    }
}

// ---------------- Aggregation: out[i] = dinv[i]*(sum_{src->i} h[src]*dinv[src] + h[i]*dinv[i]) ----------------
// one wave per node: 16 feature lanes x 4 edge slices

__global__ void __launch_bounds__(256) k_agg(const float* __restrict__ hin,
                                             const int* __restrict__ rowptr,
                                             const int* __restrict__ ssrc,
                                             const float* __restrict__ dinv,
                                             const float* __restrict__ bias,
                                             float* __restrict__ hout, int do_relu) {
    int l = threadIdx.x & 63;
    int node = blockIdx.x * 4 + (threadIdx.x >> 6);
    if (node >= NN) return;
    int j = l & 15;
    int ec = l >> 4;
    float di = dinv[node];
    int s = rowptr[node];
    int epos = rowptr[node + 1];
    float acc = (ec == 0) ? hin[(size_t)node * NH + j] * di : 0.0f;
#pragma unroll 4
    for (int e = s + ec; e < epos; e += 4) {
        int src = ssrc[e];
        acc += hin[(size_t)src * NH + j] * dinv[src];
    }
    acc += __shfl_xor(acc, 16, 64);
    acc += __shfl_xor(acc, 32, 64);
    if (ec == 0) {
        float o = acc * di + (bias ? bias[j] : 0.0f);
        if (do_relu) o = fmaxf(o, 0.0f);
        hout[(size_t)node * NH + j] = o;
    }
}

// ---------------- Final: out = log_softmax(z2 @ W2 + b2) ----------------

__global__ void __launch_bounds__(256) k_out(const float* __restrict__ z2,
                                             const float* __restrict__ W2,
                                             const float* __restrict__ b2,
                                             float* __restrict__ out) {
    __shared__ float w[NH * NC];
    __shared__ float bb[NC];
    for (int i = threadIdx.x; i < NH * NC; i += 256) w[i] = W2[i];
    if (threadIdx.x < NC) bb[threadIdx.x] = b2[threadIdx.x];
    __syncthreads();
    int node = blockIdx.x * 256 + threadIdx.x;
    if (node >= NN) return;
    float z[NH];
    const f32x4* zp = (const f32x4*)(z2 + (size_t)node * NH);
#pragma unroll
    for (int q = 0; q < 4; ++q) {
        f32x4 v = zp[q];
        z[q * 4 + 0] = v.x; z[q * 4 + 1] = v.y; z[q * 4 + 2] = v.z; z[q * 4 + 3] = v.w;
    }
    float logit[NC];
#pragma unroll
    for (int c = 0; c < NC; ++c) logit[c] = bb[c];
#pragma unroll
    for (int k = 0; k < NH; ++k) {
        float zv = z[k];
#pragma unroll
        for (int c = 0; c < NC; ++c) logit[c] += zv * w[k * NC + c];
    }
    float mx = logit[0];
#pragma unroll
    for (int c = 1; c < NC; ++c) mx = fmaxf(mx, logit[c]);
    float sum = 0.f;
#pragma unroll
    for (int c = 0; c < NC; ++c) sum += __expf(logit[c] - mx);
    float lse = mx + __logf(sum);
    float* op = out + (size_t)node * NC;
#pragma unroll
    for (int c = 0; c < NC; ++c) op[c] = logit[c] - lse;
}

// ---------------- launch ----------------

extern "C" void kernel_launch(void* const* d_in, const int* in_sizes, int n_in,
                              void* d_out, int out_size, void* d_ws, size_t ws_size,
                              hipStream_t stream) {
    const float* x  = (const float*)d_in[0];
    const int*   ei = (const int*)d_in[1];
    const float* W1 = (const float*)d_in[2];
    const float* b1 = (const float*)d_in[3];
    const float* W2 = (const float*)d_in[4];
    const float* b2 = (const float*)d_in[5];
    float* out = (float*)d_out;

    char* ws = (char*)d_ws;
    size_t off = 0;
    auto alloc = [&](size_t bytes) -> void* {
        void* p = ws + off;
        off += (bytes + 255) & ~(size_t)255;
        return p;
    };
    int* cnt        = (int*)alloc((size_t)NN * 4);
    int* rowptr     = (int*)alloc((size_t)(NN + 1) * 4);
    int* fillpos    = (int*)alloc((size_t)NN * 4);
    int* bsum       = (int*)alloc(512 * 4);
    float* dinv     = (float*)alloc((size_t)NN * 4);
    unsigned short* w1p = (unsigned short*)alloc(16 * 64 * 8 * 2);
    int* ssrc       = (int*)alloc((size_t)NE * 4);
    float* h1       = (float*)alloc((size_t)NN * NH * 4);   // reused as z2
    float* r1       = (float*)alloc((size_t)NN * NH * 4);

    int nb = (NN + 255) / 256;          // 391
    int ebl = (NE + 255) / 256;         // 12500

    hipMemsetAsync(cnt, 0, (size_t)NN * 4, stream);
    k_packW1<<<32, 256, 0, stream>>>(W1, w1p);
    k_hist<<<ebl, 256, 0, stream>>>(ei, cnt);
    k_bsum<<<nb, 256, 0, stream>>>(cnt, bsum);
    k_scanb<<<1, 512, 0, stream>>>(bsum, nb);
    k_scanc<<<nb, 256, 0, stream>>>(cnt, bsum, rowptr, fillpos, dinv);
    k_fill<<<ebl, 256, 0, stream>>>(ei, fillpos, ssrc);
    k_gemm1<<<(NN + 63) / 64, 256, 0, stream>>>(x, w1p, h1);
    k_agg<<<NN / 4, 256, 0, stream>>>(h1, rowptr, ssrc, dinv, b1, r1, 1);
    k_agg<<<NN / 4, 256, 0, stream>>>(r1, rowptr, ssrc, dinv, nullptr, h1, 0);
    k_out<<<nb, 256, 0, stream>>>(h1, W2, b2, out);
}